// Round 1
// baseline (380.897 us; speedup 1.0000x reference)
//
#include <hip/hip_runtime.h>

// Problem constants (from reference)
#define B 32
#define T 2048
#define D 1024          // D_TOKEN == N_HEADS * D_HEAD

constexpr int TCHUNK = 64;           // tokens per block in the partial reduction
constexpr int NTC    = T / TCHUNK;   // 32 t-chunks per batch

// ---------------------------------------------------------------------------
// Kernel 1: p[b,tc,d] = sum_{t in chunk tc} x[b,t,d]
// grid = B * NTC = 1024 blocks (4/CU, 16 waves/CU), 256 threads;
// thread i owns d = 4i..4i+3. Each block reads 256 KB contiguous, writes 4 KB.
// Dual accumulators halve the dependent-add chain; 8 loads in flight per wave.
// ---------------------------------------------------------------------------
__global__ __launch_bounds__(256) void reduce_tokens_partial(const float* __restrict__ x,
                                                             float* __restrict__ p) {
    const int blk = blockIdx.x;
    const int b   = blk >> 5;          // blk / NTC   (NTC == 32)
    const int tc  = blk & (NTC - 1);   // blk % NTC
    const int d4  = threadIdx.x * 4;

    const float* base = x + ((size_t)b * T + (size_t)tc * TCHUNK) * D + d4;

    float4 acc0 = make_float4(0.f, 0.f, 0.f, 0.f);
    float4 acc1 = make_float4(0.f, 0.f, 0.f, 0.f);
    #pragma unroll 4
    for (int t = 0; t < TCHUNK; t += 2) {
        float4 v0 = *(const float4*)(base + (size_t)t * D);
        float4 v1 = *(const float4*)(base + (size_t)(t + 1) * D);
        acc0.x += v0.x; acc0.y += v0.y; acc0.z += v0.z; acc0.w += v0.w;
        acc1.x += v1.x; acc1.y += v1.y; acc1.z += v1.z; acc1.w += v1.w;
    }
    acc0.x += acc1.x; acc0.y += acc1.y; acc0.z += acc1.z; acc0.w += acc1.w;

    *(float4*)(p + ((size_t)b * NTC + tc) * D + d4) = acc0;
}

// ---------------------------------------------------------------------------
// Kernel 2: s[b,d] = sum_tc p[b,tc,d]   (4 MB read, 128 KB write)
// grid = 32 blocks x 256 threads; thread owns one float4 column (b, d4..d4+3).
// Wave reads 1 KB contiguous per instruction (was 256 B scalar).
// ---------------------------------------------------------------------------
__global__ __launch_bounds__(256) void reduce_partials(const float* __restrict__ p,
                                                       float* __restrict__ s) {
    const int col = blockIdx.x * 256 + threadIdx.x;  // float4 column id, 0..8191
    const int b   = col >> 8;                        // 256 float4 per batch row
    const int d4  = (col & 255) * 4;

    const float* pp = p + (size_t)b * NTC * D + d4;
    float4 acc = make_float4(0.f, 0.f, 0.f, 0.f);
    #pragma unroll 8
    for (int tc = 0; tc < NTC; ++tc) {
        float4 v = *(const float4*)(pp + (size_t)tc * D);
        acc.x += v.x; acc.y += v.y; acc.z += v.z; acc.w += v.w;
    }
    *(float4*)(s + (size_t)b * D + d4) = acc;
}

// ---------------------------------------------------------------------------
// Kernels 3 & 4: out[b,c] = sum_d A[b,d] * W[c,d]  (+ bias[c])
// Block = 256 threads (4 waves). Block handles batch-group of 8 (bg = blk & 3)
// and 4 consecutive c (one per wave). The 8x1024 A-slice (32 KB, contiguous in
// memory) is staged once into LDS; each wave then reads W[c,:] once and all 8
// batches from LDS (contiguous ds_read_b128, conflict-free).
// 4 consecutive blocks share the same W rows -> L2 locality.
// L2 traffic ~3x lower than the previous per-wave-A version.
// ---------------------------------------------------------------------------
__global__ __launch_bounds__(256) void gemv_b8(const float* __restrict__ A,
                                               const float* __restrict__ W,
                                               const float* __restrict__ bias,
                                               float* __restrict__ out,
                                               int has_bias) {
    __shared__ float4 lds[2048];            // 8 batches x 1024 floats = 32 KB

    const int bg   = blockIdx.x & 3;        // batch group (8 batches each)
    const int c    = (blockIdx.x >> 2) * 4 + (threadIdx.x >> 6);
    const int lane = threadIdx.x & 63;
    const int b0   = bg * 8;

    // Stage A[b0 : b0+8, :] -- a contiguous 32 KB block -- into LDS.
    const float4* a4 = (const float4*)(A + (size_t)b0 * D);
    #pragma unroll
    for (int k = 0; k < 8; ++k)
        lds[k * 256 + threadIdx.x] = a4[k * 256 + threadIdx.x];
    __syncthreads();

    const float4* w4 = (const float4*)(W + (size_t)c * D);

    float acc[8] = {0.f, 0.f, 0.f, 0.f, 0.f, 0.f, 0.f, 0.f};
    #pragma unroll
    for (int k = 0; k < 4; ++k) {
        float4 wv = w4[k * 64 + lane];
        #pragma unroll
        for (int j = 0; j < 8; ++j) {
            float4 av = lds[j * 256 + k * 64 + lane];
            acc[j] += av.x * wv.x + av.y * wv.y + av.z * wv.z + av.w * wv.w;
        }
    }

    #pragma unroll
    for (int off = 32; off > 0; off >>= 1) {
        #pragma unroll
        for (int j = 0; j < 8; ++j)
            acc[j] += __shfl_xor(acc[j], off, 64);
    }

    if (lane == 0) {
        const float bb = has_bias ? bias[c] : 0.f;
        #pragma unroll
        for (int j = 0; j < 8; ++j)
            out[(size_t)(b0 + j) * D + c] = acc[j] + bb;
    }
}

extern "C" void kernel_launch(void* const* d_in, const int* in_sizes, int n_in,
                              void* d_out, int out_size, void* d_ws, size_t ws_size,
                              hipStream_t stream) {
    const float* x  = (const float*)d_in[0];  // [B, T, D]
    const float* Wh = (const float*)d_in[1];  // [N, Dh, D] == [D, D] flat (c = n*64+h)
    const float* Wp = (const float*)d_in[2];  // [D, D]
    const float* bp = (const float*)d_in[3];  // [D]
    float* out = (float*)d_out;               // [B, D]

    float* p   = (float*)d_ws;                // [B, NTC, D] partial token sums (4 MB)
    float* s   = p + (size_t)B * NTC * D;     // [B, D] token sums
    float* tmp = s + (size_t)B * D;           // [B, D] concat-head activations

    reduce_tokens_partial<<<B * NTC, 256, 0, stream>>>(x, p);
    reduce_partials<<<32, 256, 0, stream>>>(p, s);
    gemv_b8<<<1024, 256, 0, stream>>>(s,   Wh, nullptr, tmp, 0);
    gemv_b8<<<1024, 256, 0, stream>>>(tmp, Wp, bp,      out, 1);
}